// Round 8
// baseline (1634.345 us; speedup 1.0000x reference)
//
#include <hip/hip_runtime.h>
#include <math.h>

#define DIM 66
#define NPATH 17
#define WNUM 648
#define NHID 32
#define H1ROWS 384   // paths 0..7  (weight rows 0..383)
#define H2ROWS 264   // paths 8..16 (weight rows 384..647)

// ---------------- CG computation (device, mirrors reference exactly) ----------------

__device__ double dfact(int n){ double f=1.0; for(int i=2;i<=n;i++) f*=(double)i; return f; }

__device__ double su2_cg(int j1,int j2,int j3,int m1,int m2,int m3){
  if(m1+m2!=m3) return 0.0;
  double pre = sqrt((double)(2*j3+1)*dfact(j3+j1-j2)*dfact(j3-j1+j2)*dfact(j1+j2-j3)/dfact(j1+j2+j3+1));
  pre *= sqrt(dfact(j3+m3)*dfact(j3-m3)*dfact(j1-m1)*dfact(j1+m1)*dfact(j2-m2)*dfact(j2+m2));
  double s=0.0;
  for(int k=0;k<=j1+j2-j3;k++){
    int a0=k, a1=j1+j2-j3-k, a2=j1-m1-k, a3=j2+m2-k, a4=j3-j2+m1+k, a5=j3-j1-m2+k;
    if(a0<0||a1<0||a2<0||a3<0||a4<0||a5<0) continue;
    double d = dfact(a0)*dfact(a1)*dfact(a2)*dfact(a3)*dfact(a4)*dfact(a5);
    s += ((k&1)? -1.0:1.0)/d;
  }
  return pre*s;
}

// U_real(l)[row,col] (complex); row m = row-l
__device__ void u_real_entry(int l, int row, int col, double& re, double& im){
  re=0.0; im=0.0;
  const double sq = 0.7071067811865476;
  int m = row - l;
  if(m>0){
    if(col==l+m) re = ((m&1)? -sq : sq);
    else if(col==l-m) re = sq;
  } else if(m==0){
    if(col==l) re = 1.0;
  } else {
    int am = -m;
    if(col==l+m) im = sq;                      // 1j*sq
    else if(col==l-m) im = ((am&1)? sq : -sq); // -1j*(-1)^m*sq
  }
}

__constant__ int c_l1[NPATH]   = {0,0,0,1,1,1,1,1,1,1,1,1,2,2,2,2,2};
__constant__ int c_l2[NPATH]   = {0,1,2,0,1,1,1,2,0,1,2,2,0,1,2,2,2};
__constant__ int c_l3[NPATH]   = {0,1,2,1,0,1,2,1,1,1,1,2,2,1,0,1,2};
__constant__ int c_cgoff[NPATH]= {0,1,10,35,44,53,80,125,170,179,206,251,326,351,396,421,496};

__global__ void cg_init_kernel(float* __restrict__ cg_out){
  int p = blockIdx.x;
  int l1=c_l1[p], l2=c_l2[p], l3=c_l3[p];
  int n1=2*l1+1, n2=2*l2+1, n3=2*l3+1;
  int ntot=n1*n2*n3;
  __shared__ double Cc[125];
  __shared__ double red[128];
  int t=threadIdx.x;
  if(t<ntot){
    int i=t/(n2*n3), j=(t/n3)%n2, k=t%n3;
    Cc[t] = su2_cg(l1,l2,l3,i-l1,j-l2,k-l3);
  }
  __syncthreads();
  double Tre=0.0, Tim=0.0;
  if(t<ntot){
    int a=t/(n2*n3), b=(t/n3)%n2, c=t%n3;
    for(int i=0;i<n1;i++)for(int j=0;j<n2;j++)for(int k=0;k<n3;k++){
      double cc=Cc[(i*n2+j)*n3+k];
      if(cc==0.0) continue;
      double u1r,u1i,u2r,u2i,u3r,u3i;
      u_real_entry(l1,a,i,u1r,u1i); u1i=-u1i;   // conj
      u_real_entry(l2,b,j,u2r,u2i); u2i=-u2i;   // conj
      u_real_entry(l3,c,k,u3r,u3i);
      double pr=u1r*u2r-u1i*u2i, pi=u1r*u2i+u1i*u2r;
      double qr=pr*u3r-pi*u3i,   qi=pr*u3i+pi*u3r;
      Tre+=qr*cc; Tim+=qi*cc;
    }
  }
  red[t]=fabs(Tre); __syncthreads();
  for(int s=64;s>0;s>>=1){ if(t<s) red[t]+=red[t+s]; __syncthreads(); }
  double sar=red[0]; __syncthreads();
  red[t]=fabs(Tim); __syncthreads();
  for(int s=64;s>0;s>>=1){ if(t<s) red[t]+=red[t+s]; __syncthreads(); }
  double sai=red[0]; __syncthreads();
  double chosen = (sar>=sai)? Tre : Tim;
  red[t]=chosen*chosen; __syncthreads();
  for(int s=64;s>0;s>>=1){ if(t<s) red[t]+=red[t+s]; __syncthreads(); }
  double nrm=sqrt(red[0]);
  if(t<ntot) cg_out[c_cgoff[p]+t] = (float)(chosen/nrm);
}

// ---------------- rad_w2 transpose (+ fold 1/sqrt(32)) ----------------

__global__ void w2t_kernel(const float* __restrict__ w2, float* __restrict__ w2t){
  int i=blockIdx.x*blockDim.x+threadIdx.x;
  if(i<WNUM*NHID){
    int t=i/WNUM, c=i%WNUM;
    w2t[c*NHID+t]=w2[i]*0.17677669529663687f; // 1/sqrt(32)
  }
}

// ---------------- per-node linears: h_in (lin_in) to ws, res to d_out ----------------

__global__ void linear_kernel(const float* __restrict__ h,
  const float* __restrict__ w0i, const float* __restrict__ w1oi, const float* __restrict__ w1ei,
  const float* __restrict__ w2i, const float* __restrict__ b0i,
  const float* __restrict__ w0r, const float* __restrict__ w1or_, const float* __restrict__ w1er,
  const float* __restrict__ w2r, const float* __restrict__ b0r,
  float* __restrict__ h_in, float* __restrict__ out, int total)
{
  int idx=blockIdx.x*blockDim.x+threadIdx.x;
  if(idx>=total) return;
  int d = idx % DIM;
  long bn = idx / DIM;
  const float* hr = h + bn*(long)DIM;
  float s1=0.f, s2=0.f, o1, o2;
  if(d<12){
    #pragma unroll
    for(int u=0;u<12;u++){ float xv=hr[u]; s1+=xv*w0i[u*12+d]; s2+=xv*w0r[u*12+d]; }
    const float r = 0.28867513459481287f; // 1/sqrt(12)
    o1 = s1*r + b0i[d]; o2 = s2*r + b0r[d];
  } else if(d<24){
    int rel=d-12, v=rel/3, i=rel%3;
    #pragma unroll
    for(int u=0;u<4;u++){ float xv=hr[12+u*3+i]; s1+=xv*w1oi[u*4+v]; s2+=xv*w1or_[u*4+v]; }
    o1=s1*0.5f; o2=s2*0.5f;
  } else if(d<36){
    int rel=d-24, v=rel/3, i=rel%3;
    #pragma unroll
    for(int u=0;u<4;u++){ float xv=hr[24+u*3+i]; s1+=xv*w1ei[u*4+v]; s2+=xv*w1er[u*4+v]; }
    o1=s1*0.5f; o2=s2*0.5f;
  } else {
    int rel=d-36, v=rel/5, i=rel%5;
    #pragma unroll
    for(int u=0;u<6;u++){ float xv=hr[36+u*5+i]; s1+=xv*w2i[u*6+v]; s2+=xv*w2r[u*6+v]; }
    const float r=0.4082482904638631f; // 1/sqrt(6)
    o1=s1*r; o2=s2*r;
  }
  h_in[idx]=o1; out[idx]=o2;
}

// ---------------- fused edge kernel: W in LDS, broadcast reads ----------------
// One thread per edge; all (path,u,v,t) loop indices are lockstep-uniform across
// the wave, so every LDS read of W/cg is a same-address broadcast (no conflicts,
// one issue serves 64 edges). Weight traffic: 83 KB per wave-pass, not per edge.

template<int L1_,int L2_,int L3_,int MUL1,int MULO,int XOFF,int YOFF,int OOFF,int WROW,int CGOFF>
__device__ __forceinline__ void do_path_lds(const float* __restrict__ hs, const float* Y,
  const float* __restrict__ hid, const float* Wl, const float* cgl, float* acc)
{
  constexpr int N1=2*L1_+1, N2=2*L2_+1, N3=2*L3_+1;
  float M[N1*N3];
  #pragma unroll
  for(int i=0;i<N1;i++){
    #pragma unroll
    for(int k=0;k<N3;k++){
      float s=0.f;
      #pragma unroll
      for(int j=0;j<N2;j++) s += Y[YOFF+j]*cgl[CGOFF+(i*N2+j)*N3+k];
      M[i*N3+k]=s;
    }
  }
  for(int u=0;u<MUL1;u++){   // rolled: keeps code compact; hs is a pointer (L1)
    float zt[N3];
    #pragma unroll
    for(int k=0;k<N3;k++){
      float s=0.f;
      #pragma unroll
      for(int i=0;i<N1;i++) s += hs[XOFF+u*N1+i]*M[i*N3+k];
      zt[k]=s;
    }
    #pragma unroll
    for(int v=0;v<MULO;v++){
      const float4* wr = (const float4*)(Wl + (WROW + u*MULO + v)*NHID);
      float wv=0.f;
      #pragma unroll
      for(int q=0;q<8;q++){
        float4 w = wr[q];   // ds_read_b128, wave-uniform address -> broadcast
        wv += w.x*hid[4*q] + w.y*hid[4*q+1] + w.z*hid[4*q+2] + w.w*hid[4*q+3];
      }
      #pragma unroll
      for(int k=0;k<N3;k++) acc[OOFF+v*N3+k] += zt[k]*wv;
    }
  }
}

__global__ __launch_bounds__(512) void edge_fused_kernel(
  const float* __restrict__ h_in, const int* __restrict__ e_src, const int* __restrict__ e_dst,
  const float* __restrict__ e_attr, const float* __restrict__ rad_w1,
  const float* __restrict__ w2t, const float* __restrict__ cg, float* __restrict__ out,
  int BE, int N, int E, int per_block)
{
  __shared__ float Wl[H1ROWS*NHID];   // 48 KB, reused for half2
  __shared__ float cgl[640];
  __shared__ float rw1l[NHID];
  int tid = threadIdx.x;

  for(int i=tid; i<621; i+=512) cgl[i] = cg[i];   // FIX: loop, not tid<621 guard
  if(tid < NHID) rw1l[tid] = rad_w1[tid];

  float4* Wl4 = (float4*)Wl;
  const float4* w4 = (const float4*)w2t;

  for(int base = 0; base < per_block; base += 512){
    int el = blockIdx.x*per_block + base + tid;
    bool active = (base + tid < per_block) && (el < BE);

    // ---- stage W half 1 (paths 0..7) ----
    __syncthreads();                       // prior round / cgl staging done
    for(int i=tid; i<H1ROWS*NHID/4; i+=512) Wl4[i] = w4[i];
    __syncthreads();

    // ---- per-edge setup ----
    int b=0, src=0, dst=0;
    float x=0.f, y=0.f, z=0.f;
    if(active){
      b = el / E;
      src = e_src[el]; dst = e_dst[el];
      const float* ea = e_attr + (long)el*3;
      x=ea[0]; y=ea[1]; z=ea[2];
    }
    float rn = sqrtf(x*x+y*y+z*z) + 1e-8f;
    float xh=x/rn, yh=y/rn, zh=z/rn;
    float Y[9];
    const float s3=1.7320508075688772f, s5=2.23606797749979f, s15=3.872983346207417f;
    Y[0]=1.f; Y[1]=s3*yh; Y[2]=s3*zh; Y[3]=s3*xh;
    Y[4]=s15*xh*yh; Y[5]=s15*yh*zh; Y[6]=0.5f*s5*(3.f*zh*zh-1.f);
    Y[7]=s15*xh*zh; Y[8]=0.5f*s15*(xh*xh-yh*yh);
    float hid[NHID];
    #pragma unroll
    for(int t=0;t<NHID;t++){ float a = rn*rw1l[t]; hid[t]=a/(1.f+expf(-a)); }
    const float* hs = h_in + ((long)b*N + src)*DIM;  // pointer: L1-cached, no scratch
    float acc[DIM];
    #pragma unroll
    for(int d=0;d<DIM;d++) acc[d]=0.f;

    // ---- half 1: paths 0..7 ----
    //              L1 L2 L3 M1 MO  XO YO OO WROW CGOFF
    do_path_lds<0,0,0,12,12,  0,0, 0,   0,   0>(hs,Y,hid,Wl,cgl,acc);
    do_path_lds<0,1,1,12, 4,  0,1,12, 144,   1>(hs,Y,hid,Wl,cgl,acc);
    do_path_lds<0,2,2,12, 6,  0,4,36, 192,  10>(hs,Y,hid,Wl,cgl,acc);
    do_path_lds<1,0,1, 4, 4, 12,0,12, 264,  35>(hs,Y,hid,Wl,cgl,acc);
    do_path_lds<1,1,0, 4,12, 12,1, 0, 280,  44>(hs,Y,hid,Wl,cgl,acc);
    do_path_lds<1,1,1, 4, 4, 12,1,24, 328,  53>(hs,Y,hid,Wl,cgl,acc);
    do_path_lds<1,1,2, 4, 6, 12,1,36, 344,  80>(hs,Y,hid,Wl,cgl,acc);
    do_path_lds<1,2,1, 4, 4, 12,4,12, 368, 125>(hs,Y,hid,Wl,cgl,acc);

    // ---- stage W half 2 (paths 8..16, rows 384..647) ----
    __syncthreads();
    for(int i=tid; i<H2ROWS*NHID/4; i+=512) Wl4[i] = w4[H1ROWS*NHID/4 + i];
    __syncthreads();

    // WROW here is row offset minus 384
    do_path_lds<1,0,1, 4, 4, 24,0,24,   0, 170>(hs,Y,hid,Wl,cgl,acc);
    do_path_lds<1,1,1, 4, 4, 24,1,12,  16, 179>(hs,Y,hid,Wl,cgl,acc);
    do_path_lds<1,2,1, 4, 4, 24,4,24,  32, 206>(hs,Y,hid,Wl,cgl,acc);
    do_path_lds<1,2,2, 4, 6, 24,4,36,  48, 251>(hs,Y,hid,Wl,cgl,acc);
    do_path_lds<2,0,2, 6, 6, 36,0,36,  72, 326>(hs,Y,hid,Wl,cgl,acc);
    do_path_lds<2,1,1, 6, 4, 36,1,12, 108, 351>(hs,Y,hid,Wl,cgl,acc);
    do_path_lds<2,2,0, 6,12, 36,4, 0, 132, 396>(hs,Y,hid,Wl,cgl,acc);
    do_path_lds<2,2,1, 6, 4, 36,4,24, 204, 421>(hs,Y,hid,Wl,cgl,acc);
    do_path_lds<2,2,2, 6, 6, 36,4,36, 228, 496>(hs,Y,hid,Wl,cgl,acc);

    // ---- scatter ----
    if(active){
      const float a0=0.21320071635561044f; // sqrt(1/22)
      const float a1=0.31622776601683794f; // sqrt(3/30)
      const float a2=0.4082482904638631f;  // sqrt(3/18)
      const float a3=0.3952847075210474f;  // sqrt(5/32)
      float* op = out + ((long)b*N + dst)*DIM;
      #pragma unroll
      for(int d=0;d<12;d++)  unsafeAtomicAdd(&op[d], acc[d]*a0);
      #pragma unroll
      for(int d=12;d<24;d++) unsafeAtomicAdd(&op[d], acc[d]*a1);
      #pragma unroll
      for(int d=24;d<36;d++) unsafeAtomicAdd(&op[d], acc[d]*a2);
      #pragma unroll
      for(int d=36;d<66;d++) unsafeAtomicAdd(&op[d], acc[d]*a3);
    }
  }
}

// ---------------- norm_act (in place on d_out) ----------------

__global__ void norm_act_kernel(float* __restrict__ out, int total){
  int idx=blockIdx.x*blockDim.x+threadIdx.x;
  if(idx>=total) return;
  int c = idx % 26; long bn = idx / 26;
  int off, len;
  if(c<12){ off=c; len=1; }
  else if(c<16){ off=12+(c-12)*3; len=3; }
  else if(c<20){ off=24+(c-16)*3; len=3; }
  else { off=36+(c-20)*5; len=5; }
  float* p = out + bn*(long)DIM + off;
  float sum=0.f;
  for(int i=0;i<len;i++){ float v=p[i]; sum+=v*v; }
  float n = sqrtf(sum+1e-12f);
  float sc = 1.f/(1.f+expf(-n));  // silu(n)/n = sigmoid(n)
  for(int i=0;i<len;i++) p[i]*=sc;
}

// ---------------- launch ----------------

extern "C" void kernel_launch(void* const* d_in, const int* in_sizes, int n_in,
                              void* d_out, int out_size, void* d_ws, size_t ws_size,
                              hipStream_t stream)
{
  const float* h       = (const float*)d_in[0];
  const int*   e_src   = (const int*)  d_in[1];
  const int*   e_dst   = (const int*)  d_in[2];
  const float* e_attr  = (const float*)d_in[3];
  const float* lw0     = (const float*)d_in[4];
  const float* lw1o    = (const float*)d_in[5];
  const float* lw1e    = (const float*)d_in[6];
  const float* lw2     = (const float*)d_in[7];
  const float* lb0     = (const float*)d_in[8];
  const float* rw0     = (const float*)d_in[9];
  const float* rw1o    = (const float*)d_in[10];
  const float* rw1e    = (const float*)d_in[11];
  const float* rw2     = (const float*)d_in[12];
  const float* rb0     = (const float*)d_in[13];
  const float* rad_w1  = (const float*)d_in[14];
  const float* rad_w2  = (const float*)d_in[15];

  const int B  = 2;
  const int BE = in_sizes[1];        // B*E
  const int E  = BE / B;
  const int BN = in_sizes[0] / DIM;  // B*N
  const int N  = BN / B;

  float* ws   = (float*)d_ws;
  float* h_in = ws;                                   // BN*DIM floats
  float* cg   = ws + (size_t)BN*DIM;                  // 621 floats (pad to 640)
  float* w2t  = cg + 640;                             // WNUM*NHID floats

  cg_init_kernel<<<NPATH, 128, 0, stream>>>(cg);
  int w2n = WNUM*NHID;
  w2t_kernel<<<(w2n+255)/256, 256, 0, stream>>>(rad_w2, w2t);
  int totL = BN*DIM;
  linear_kernel<<<(totL+255)/256, 256, 0, stream>>>(h, lw0, lw1o, lw1e, lw2, lb0,
                                                    rw0, rw1o, rw1e, rw2, rb0,
                                                    h_in, (float*)d_out, totL);
  const int NBLK = 256;                       // 1 block per CU, balanced edges
  int per_block = (BE + NBLK - 1) / NBLK;
  edge_fused_kernel<<<NBLK, 512, 0, stream>>>(h_in, e_src, e_dst, e_attr,
                                              rad_w1, w2t, cg, (float*)d_out,
                                              BE, N, E, per_block);
  int totN = BN*26;
  norm_act_kernel<<<(totN+255)/256, 256, 0, stream>>>((float*)d_out, totN);
}

// Round 9
// 590.846 us; speedup vs baseline: 2.7661x; 2.7661x over previous
//
#include <hip/hip_runtime.h>
#include <math.h>

#define DIM 66
#define NPATH 17
#define WNUM 648
#define NHID 32
#define G0R 264   // group-0 weight rows (max) -> LDS buffer size
#define G1R 120
#define G2R 72
#define G3R 192

// ---------------- CG computation (device, mirrors reference exactly) ----------------

__device__ double dfact(int n){ double f=1.0; for(int i=2;i<=n;i++) f*=(double)i; return f; }

__device__ double su2_cg(int j1,int j2,int j3,int m1,int m2,int m3){
  if(m1+m2!=m3) return 0.0;
  double pre = sqrt((double)(2*j3+1)*dfact(j3+j1-j2)*dfact(j3-j1+j2)*dfact(j1+j2-j3)/dfact(j1+j2+j3+1));
  pre *= sqrt(dfact(j3+m3)*dfact(j3-m3)*dfact(j1-m1)*dfact(j1+m1)*dfact(j2-m2)*dfact(j2+m2));
  double s=0.0;
  for(int k=0;k<=j1+j2-j3;k++){
    int a0=k, a1=j1+j2-j3-k, a2=j1-m1-k, a3=j2+m2-k, a4=j3-j2+m1+k, a5=j3-j1-m2+k;
    if(a0<0||a1<0||a2<0||a3<0||a4<0||a5<0) continue;
    double d = dfact(a0)*dfact(a1)*dfact(a2)*dfact(a3)*dfact(a4)*dfact(a5);
    s += ((k&1)? -1.0:1.0)/d;
  }
  return pre*s;
}

// U_real(l)[row,col] (complex); row m = row-l
__device__ void u_real_entry(int l, int row, int col, double& re, double& im){
  re=0.0; im=0.0;
  const double sq = 0.7071067811865476;
  int m = row - l;
  if(m>0){
    if(col==l+m) re = ((m&1)? -sq : sq);
    else if(col==l-m) re = sq;
  } else if(m==0){
    if(col==l) re = 1.0;
  } else {
    int am = -m;
    if(col==l+m) im = sq;                      // 1j*sq
    else if(col==l-m) im = ((am&1)? sq : -sq); // -1j*(-1)^m*sq
  }
}

__constant__ int c_l1[NPATH]   = {0,0,0,1,1,1,1,1,1,1,1,1,2,2,2,2,2};
__constant__ int c_l2[NPATH]   = {0,1,2,0,1,1,1,2,0,1,2,2,0,1,2,2,2};
__constant__ int c_l3[NPATH]   = {0,1,2,1,0,1,2,1,1,1,1,2,2,1,0,1,2};
__constant__ int c_cgoff[NPATH]= {0,1,10,35,44,53,80,125,170,179,206,251,326,351,396,421,496};

__global__ void cg_init_kernel(float* __restrict__ cg_out){
  int p = blockIdx.x;
  int l1=c_l1[p], l2=c_l2[p], l3=c_l3[p];
  int n1=2*l1+1, n2=2*l2+1, n3=2*l3+1;
  int ntot=n1*n2*n3;
  __shared__ double Cc[125];
  __shared__ double red[128];
  int t=threadIdx.x;
  if(t<ntot){
    int i=t/(n2*n3), j=(t/n3)%n2, k=t%n3;
    Cc[t] = su2_cg(l1,l2,l3,i-l1,j-l2,k-l3);
  }
  __syncthreads();
  double Tre=0.0, Tim=0.0;
  if(t<ntot){
    int a=t/(n2*n3), b=(t/n3)%n2, c=t%n3;
    for(int i=0;i<n1;i++)for(int j=0;j<n2;j++)for(int k=0;k<n3;k++){
      double cc=Cc[(i*n2+j)*n3+k];
      if(cc==0.0) continue;
      double u1r,u1i,u2r,u2i,u3r,u3i;
      u_real_entry(l1,a,i,u1r,u1i); u1i=-u1i;   // conj
      u_real_entry(l2,b,j,u2r,u2i); u2i=-u2i;   // conj
      u_real_entry(l3,c,k,u3r,u3i);
      double pr=u1r*u2r-u1i*u2i, pi=u1r*u2i+u1i*u2r;
      double qr=pr*u3r-pi*u3i,   qi=pr*u3i+pi*u3r;
      Tre+=qr*cc; Tim+=qi*cc;
    }
  }
  red[t]=fabs(Tre); __syncthreads();
  for(int s=64;s>0;s>>=1){ if(t<s) red[t]+=red[t+s]; __syncthreads(); }
  double sar=red[0]; __syncthreads();
  red[t]=fabs(Tim); __syncthreads();
  for(int s=64;s>0;s>>=1){ if(t<s) red[t]+=red[t+s]; __syncthreads(); }
  double sai=red[0]; __syncthreads();
  double chosen = (sar>=sai)? Tre : Tim;
  red[t]=chosen*chosen; __syncthreads();
  for(int s=64;s>0;s>>=1){ if(t<s) red[t]+=red[t+s]; __syncthreads(); }
  double nrm=sqrt(red[0]);
  if(t<ntot) cg_out[c_cgoff[p]+t] = (float)(chosen/nrm);
}

// ------- rad_w2 repack: transpose + fold 1/sqrt(32) + group-contiguous row order -------
// New row order: [group0 rows][group1][group2][group3]; bases 0,264,384,456.

__constant__ int rp_old[NPATH] = {0,144,192,264,280,328,344,368,384,400,416,432,456,492,516,588,612};
__constant__ int rp_cnt[NPATH] = {144,48,72,16,48,16,24,16,16,16,16,24,36,24,72,24,36};
__constant__ int rp_new[NPATH] = {0,264,456,312,144,384,528,328,400,344,416,552,576,360,192,432,612};

__global__ void wg_pack_kernel(const float* __restrict__ w2, float* __restrict__ wg){
  int i=blockIdx.x*blockDim.x+threadIdx.x;
  if(i>=WNUM*NHID) return;
  int t=i/WNUM, c=i%WNUM;            // input layout [32][648]
  int nr=0;
  #pragma unroll
  for(int p=0;p<NPATH;p++)
    if(c>=rp_old[p] && c<rp_old[p]+rp_cnt[p]) nr = rp_new[p] + (c-rp_old[p]);
  wg[nr*NHID+t] = w2[i]*0.17677669529663687f; // 1/sqrt(32)
}

// ---------------- per-node linears: h_in (lin_in) to ws, res to d_out ----------------

__global__ void linear_kernel(const float* __restrict__ h,
  const float* __restrict__ w0i, const float* __restrict__ w1oi, const float* __restrict__ w1ei,
  const float* __restrict__ w2i, const float* __restrict__ b0i,
  const float* __restrict__ w0r, const float* __restrict__ w1or_, const float* __restrict__ w1er,
  const float* __restrict__ w2r, const float* __restrict__ b0r,
  float* __restrict__ h_in, float* __restrict__ out, int total)
{
  int idx=blockIdx.x*blockDim.x+threadIdx.x;
  if(idx>=total) return;
  int d = idx % DIM;
  long bn = idx / DIM;
  const float* hr = h + bn*(long)DIM;
  float s1=0.f, s2=0.f, o1, o2;
  if(d<12){
    #pragma unroll
    for(int u=0;u<12;u++){ float xv=hr[u]; s1+=xv*w0i[u*12+d]; s2+=xv*w0r[u*12+d]; }
    const float r = 0.28867513459481287f; // 1/sqrt(12)
    o1 = s1*r + b0i[d]; o2 = s2*r + b0r[d];
  } else if(d<24){
    int rel=d-12, v=rel/3, i=rel%3;
    #pragma unroll
    for(int u=0;u<4;u++){ float xv=hr[12+u*3+i]; s1+=xv*w1oi[u*4+v]; s2+=xv*w1or_[u*4+v]; }
    o1=s1*0.5f; o2=s2*0.5f;
  } else if(d<36){
    int rel=d-24, v=rel/3, i=rel%3;
    #pragma unroll
    for(int u=0;u<4;u++){ float xv=hr[24+u*3+i]; s1+=xv*w1ei[u*4+v]; s2+=xv*w1er[u*4+v]; }
    o1=s1*0.5f; o2=s2*0.5f;
  } else {
    int rel=d-36, v=rel/5, i=rel%5;
    #pragma unroll
    for(int u=0;u<6;u++){ float xv=hr[36+u*5+i]; s1+=xv*w2i[u*6+v]; s2+=xv*w2r[u*6+v]; }
    const float r=0.4082482904638631f; // 1/sqrt(6)
    o1=s1*r; o2=s2*r;
  }
  h_in[idx]=o1; out[idx]=o2;
}

// ---------------- fused edge kernel: group-phased, W in LDS (broadcast) ----------------
// Per output group: stage that group's weight rows into LDS, compute with a SMALL
// accumulator (<=30 floats), scatter that group's atomics, barrier, next group.
// All W/cg LDS reads are wave-uniform -> broadcast, no conflicts.

template<int L1_,int L2_,int L3_,int MUL1,int MULO,int XOFF,int YOFF,int WROW,int CGOFF>
__device__ __forceinline__ void do_path_g(const float* __restrict__ hs, const float* Y,
  const float* __restrict__ hid, const float* Wl, const float* cgl, float* accg)
{
  constexpr int N1=2*L1_+1, N2=2*L2_+1, N3=2*L3_+1;
  float M[N1*N3];
  #pragma unroll
  for(int i=0;i<N1;i++){
    #pragma unroll
    for(int k=0;k<N3;k++){
      float s=0.f;
      #pragma unroll
      for(int j=0;j<N2;j++) s += Y[YOFF+j]*cgl[CGOFF+(i*N2+j)*N3+k];
      M[i*N3+k]=s;
    }
  }
  for(int u=0;u<MUL1;u++){
    float zt[N3];
    #pragma unroll
    for(int k=0;k<N3;k++){
      float s=0.f;
      #pragma unroll
      for(int i=0;i<N1;i++) s += hs[XOFF+u*N1+i]*M[i*N3+k];
      zt[k]=s;
    }
    #pragma unroll
    for(int v=0;v<MULO;v++){
      const float4* wr = (const float4*)(Wl + (WROW + u*MULO + v)*NHID);
      float wv=0.f;
      #pragma unroll
      for(int q=0;q<8;q++){
        float4 w = wr[q];   // ds_read_b128, wave-uniform -> broadcast
        wv += w.x*hid[4*q] + w.y*hid[4*q+1] + w.z*hid[4*q+2] + w.w*hid[4*q+3];
      }
      #pragma unroll
      for(int k=0;k<N3;k++) accg[v*N3+k] += zt[k]*wv;
    }
  }
}

__global__ __launch_bounds__(512) void edge_fused_kernel(
  const float* __restrict__ h_in, const int* __restrict__ e_src, const int* __restrict__ e_dst,
  const float* __restrict__ e_attr, const float* __restrict__ rad_w1,
  const float* __restrict__ wg, const float* __restrict__ cg, float* __restrict__ out,
  int BE, int N, int E, int per_block)
{
  __shared__ float Wl[G0R*NHID];     // 33 KB (max group), reused per phase
  __shared__ float cgl[640];
  __shared__ float rw1l[NHID];
  int tid = threadIdx.x;

  for(int i=tid; i<621; i+=512) cgl[i] = cg[i];
  if(tid < NHID) rw1l[tid] = rad_w1[tid];

  float4* Wl4 = (float4*)Wl;
  const float4* wg4 = (const float4*)wg;

  const float a0=0.21320071635561044f; // sqrt(1/22)
  const float a1=0.31622776601683794f; // sqrt(3/30)
  const float a2=0.4082482904638631f;  // sqrt(3/18)
  const float a3=0.3952847075210474f;  // sqrt(5/32)

  for(int base = 0; base < per_block; base += 512){
    int el = blockIdx.x*per_block + base + tid;
    bool active = (base + tid < per_block) && (el < BE);

    // per-edge setup (safe defaults for inactive lanes)
    int b=0, src=0, dst=0;
    float x=0.f, y=0.f, z=0.f;
    if(active){
      b = el / E;
      src = e_src[el]; dst = e_dst[el];
      const float* ea = e_attr + (long)el*3;
      x=ea[0]; y=ea[1]; z=ea[2];
    }
    float rn = sqrtf(x*x+y*y+z*z) + 1e-8f;
    float xh=x/rn, yh=y/rn, zh=z/rn;
    float Y[9];
    const float s3=1.7320508075688772f, s5=2.23606797749979f, s15=3.872983346207417f;
    Y[0]=1.f; Y[1]=s3*yh; Y[2]=s3*zh; Y[3]=s3*xh;
    Y[4]=s15*xh*yh; Y[5]=s15*yh*zh; Y[6]=0.5f*s5*(3.f*zh*zh-1.f);
    Y[7]=s15*xh*zh; Y[8]=0.5f*s15*(xh*xh-yh*yh);
    float hid[NHID];
    #pragma unroll
    for(int t=0;t<NHID;t++){ float a = rn*rw1l[t]; hid[t]=a/(1.f+expf(-a)); }
    const float* hs = h_in + ((long)b*N + src)*DIM;
    float* op = out + ((long)b*N + dst)*DIM;

    // ===== phase 0: output group 0 (ch 0..11), rows base 0 =====
    __syncthreads();
    for(int i=tid; i<G0R*NHID/4; i+=512) Wl4[i] = wg4[i];
    __syncthreads();
    if(active){
      float accg[12];
      #pragma unroll
      for(int d=0;d<12;d++) accg[d]=0.f;
      //         L1 L2 L3 M1 MO  XO YO WROW CGOFF
      do_path_g<0,0,0,12,12,  0,0,   0,   0>(hs,Y,hid,Wl,cgl,accg);
      do_path_g<1,1,0, 4,12, 12,1, 144,  44>(hs,Y,hid,Wl,cgl,accg);
      do_path_g<2,2,0, 6,12, 36,4, 192, 396>(hs,Y,hid,Wl,cgl,accg);
      #pragma unroll
      for(int d=0;d<12;d++) unsafeAtomicAdd(&op[d], accg[d]*a0);
    }

    // ===== phase 1: output group 1 (ch 12..23), rows base 264 =====
    __syncthreads();
    for(int i=tid; i<G1R*NHID/4; i+=512) Wl4[i] = wg4[264*NHID/4 + i];
    __syncthreads();
    if(active){
      float accg[12];
      #pragma unroll
      for(int d=0;d<12;d++) accg[d]=0.f;
      do_path_g<0,1,1,12, 4,  0,1,   0,   1>(hs,Y,hid,Wl,cgl,accg);
      do_path_g<1,0,1, 4, 4, 12,0,  48,  35>(hs,Y,hid,Wl,cgl,accg);
      do_path_g<1,2,1, 4, 4, 12,4,  64, 125>(hs,Y,hid,Wl,cgl,accg);
      do_path_g<1,1,1, 4, 4, 24,1,  80, 179>(hs,Y,hid,Wl,cgl,accg);
      do_path_g<2,1,1, 6, 4, 36,1,  96, 351>(hs,Y,hid,Wl,cgl,accg);
      #pragma unroll
      for(int d=0;d<12;d++) unsafeAtomicAdd(&op[12+d], accg[d]*a1);
    }

    // ===== phase 2: output group 2 (ch 24..35), rows base 384 =====
    __syncthreads();
    for(int i=tid; i<G2R*NHID/4; i+=512) Wl4[i] = wg4[384*NHID/4 + i];
    __syncthreads();
    if(active){
      float accg[12];
      #pragma unroll
      for(int d=0;d<12;d++) accg[d]=0.f;
      do_path_g<1,1,1, 4, 4, 12,1,   0,  53>(hs,Y,hid,Wl,cgl,accg);
      do_path_g<1,0,1, 4, 4, 24,0,  16, 170>(hs,Y,hid,Wl,cgl,accg);
      do_path_g<1,2,1, 4, 4, 24,4,  32, 206>(hs,Y,hid,Wl,cgl,accg);
      do_path_g<2,2,1, 6, 4, 36,4,  48, 421>(hs,Y,hid,Wl,cgl,accg);
      #pragma unroll
      for(int d=0;d<12;d++) unsafeAtomicAdd(&op[24+d], accg[d]*a2);
    }

    // ===== phase 3: output group 3 (ch 36..65), rows base 456 =====
    __syncthreads();
    for(int i=tid; i<G3R*NHID/4; i+=512) Wl4[i] = wg4[456*NHID/4 + i];
    __syncthreads();
    if(active){
      float accg[30];
      #pragma unroll
      for(int d=0;d<30;d++) accg[d]=0.f;
      do_path_g<0,2,2,12, 6,  0,4,   0,  10>(hs,Y,hid,Wl,cgl,accg);
      do_path_g<1,1,2, 4, 6, 12,1,  72,  80>(hs,Y,hid,Wl,cgl,accg);
      do_path_g<1,2,2, 4, 6, 24,4,  96, 251>(hs,Y,hid,Wl,cgl,accg);
      do_path_g<2,0,2, 6, 6, 36,0, 120, 326>(hs,Y,hid,Wl,cgl,accg);
      do_path_g<2,2,2, 6, 6, 36,4, 156, 496>(hs,Y,hid,Wl,cgl,accg);
      #pragma unroll
      for(int d=0;d<30;d++) unsafeAtomicAdd(&op[36+d], accg[d]*a3);
    }
  }
}

// ---------------- norm_act (in place on d_out) ----------------

__global__ void norm_act_kernel(float* __restrict__ out, int total){
  int idx=blockIdx.x*blockDim.x+threadIdx.x;
  if(idx>=total) return;
  int c = idx % 26; long bn = idx / 26;
  int off, len;
  if(c<12){ off=c; len=1; }
  else if(c<16){ off=12+(c-12)*3; len=3; }
  else if(c<20){ off=24+(c-16)*3; len=3; }
  else { off=36+(c-20)*5; len=5; }
  float* p = out + bn*(long)DIM + off;
  float sum=0.f;
  for(int i=0;i<len;i++){ float v=p[i]; sum+=v*v; }
  float n = sqrtf(sum+1e-12f);
  float sc = 1.f/(1.f+expf(-n));  // silu(n)/n = sigmoid(n)
  for(int i=0;i<len;i++) p[i]*=sc;
}

// ---------------- launch ----------------

extern "C" void kernel_launch(void* const* d_in, const int* in_sizes, int n_in,
                              void* d_out, int out_size, void* d_ws, size_t ws_size,
                              hipStream_t stream)
{
  const float* h       = (const float*)d_in[0];
  const int*   e_src   = (const int*)  d_in[1];
  const int*   e_dst   = (const int*)  d_in[2];
  const float* e_attr  = (const float*)d_in[3];
  const float* lw0     = (const float*)d_in[4];
  const float* lw1o    = (const float*)d_in[5];
  const float* lw1e    = (const float*)d_in[6];
  const float* lw2     = (const float*)d_in[7];
  const float* lb0     = (const float*)d_in[8];
  const float* rw0     = (const float*)d_in[9];
  const float* rw1o    = (const float*)d_in[10];
  const float* rw1e    = (const float*)d_in[11];
  const float* rw2     = (const float*)d_in[12];
  const float* rb0     = (const float*)d_in[13];
  const float* rad_w1  = (const float*)d_in[14];
  const float* rad_w2  = (const float*)d_in[15];

  const int B  = 2;
  const int BE = in_sizes[1];        // B*E
  const int E  = BE / B;
  const int BN = in_sizes[0] / DIM;  // B*N
  const int N  = BN / B;

  float* ws   = (float*)d_ws;
  float* h_in = ws;                                   // BN*DIM floats
  float* cg   = ws + (size_t)BN*DIM;                  // 621 floats (pad to 640)
  float* wg   = cg + 640;                             // WNUM*NHID floats (group-packed)

  cg_init_kernel<<<NPATH, 128, 0, stream>>>(cg);
  int w2n = WNUM*NHID;
  wg_pack_kernel<<<(w2n+255)/256, 256, 0, stream>>>(rad_w2, wg);
  int totL = BN*DIM;
  linear_kernel<<<(totL+255)/256, 256, 0, stream>>>(h, lw0, lw1o, lw1e, lw2, lb0,
                                                    rw0, rw1o, rw1e, rw2, rb0,
                                                    h_in, (float*)d_out, totL);
  const int NBLK = 256;                       // 1 block per CU, balanced edges
  int per_block = (BE + NBLK - 1) / NBLK;
  edge_fused_kernel<<<NBLK, 512, 0, stream>>>(h_in, e_src, e_dst, e_attr,
                                              rad_w1, wg, cg, (float*)d_out,
                                              BE, N, E, per_block);
  int totN = BN*26;
  norm_act_kernel<<<(totN+255)/256, 256, 0, stream>>>((float*)d_out, totN);
}